// Round 6
// baseline (514.931 us; speedup 1.0000x reference)
//
#include <hip/hip_runtime.h>

typedef _Float16 half_t;
typedef _Float16 half4 __attribute__((ext_vector_type(4)));
typedef _Float16 half8 __attribute__((ext_vector_type(8)));
typedef float float4v __attribute__((ext_vector_type(4)));

#define MFMA16(a, b, c) __builtin_amdgcn_mfma_f32_16x16x32_f16(a, b, c, 0, 0, 0)

// ---------------------------------------------------------------------------
// pack_frags: LDS-transposed weight packing into MFMA fragment order (fp16).
//   frag: out[((nt*nks+ks)*64+lane)*8+j] = W[k = ks*32+((lane>>4)<<3)+j][n]
// w0 uses k-REORDERED index: knew = w9*64 + c  (kold = c*9 + w9) so conv_l0's
// chunk ks covers one (di,dj) shift x 32 consecutive channels.
// Block 42 handles w4 frags + w0 tail rows 576..579 (fp16 flat [4][256]).
// ---------------------------------------------------------------------------
__global__ __launch_bounds__(256) void pack_frags(
    const float* __restrict__ w0, const float* __restrict__ w1,
    const float* __restrict__ w2, const float* __restrict__ w3,
    const float* __restrict__ w4, half_t* __restrict__ w0p,
    half_t* __restrict__ w1p, half_t* __restrict__ w2p,
    half_t* __restrict__ w3p, half_t* __restrict__ w4p,
    half_t* __restrict__ wtp) {
  const int bb = blockIdx.x;
  const int tid = threadIdx.x;
  if (bb == 42) {  // w4 frags (nt=0, nks=8) + w0 tail
#pragma unroll
    for (int e = 0; e < 16; e++) {
      const int id = e * 256 + tid;
      const int j = id & 7;
      const int lane = (id >> 3) & 63;
      const int ks = id >> 9;  // 0..7
      const int n = lane & 15;
      const int k = ks * 32 + ((lane >> 4) << 3) + j;
      w4p[id] = (half_t)((n < 3) ? w4[k * 3 + n] : 0.0f);
    }
#pragma unroll
    for (int e = 0; e < 4; e++)
      wtp[e * 256 + tid] = (half_t)w0[576 * 256 + e * 256 + tid];
    return;
  }
  __shared__ float Wt[32][260];
  const float* w;
  half_t* out;
  int nks, ks;
  bool reorder = false;
  if (bb < 18) { w = w0; out = w0p; nks = 18; ks = bb; reorder = true; }
  else if (bb < 26) { w = w1; out = w1p; nks = 8; ks = bb - 18; }
  else if (bb < 34) { w = w2; out = w2p; nks = 8; ks = bb - 26; }
  else { w = w3; out = w3p; nks = 8; ks = bb - 34; }
  // stage 32x256 tile, coalesced along n
  {
    const int n4 = (tid & 63) * 4;
    const int kr = tid >> 6;  // 0..3
#pragma unroll
    for (int e = 0; e < 8; e++) {
      const int kp = e * 4 + kr;  // 0..31
      int kg = ks * 32 + kp;
      if (reorder) { const int w9 = kg >> 6, c = kg & 63; kg = c * 9 + w9; }
      *(float4v*)&Wt[kp][n4] = *(const float4v*)(w + (size_t)kg * 256 + n4);
    }
  }
  __syncthreads();
  const int lane = tid & 63;
  const int l15 = lane & 15;
  const int kq = (lane >> 4) << 3;
#pragma unroll
  for (int e = 0; e < 4; e++) {
    const int nt = e * 4 + (tid >> 6);
    half8 hv;
#pragma unroll
    for (int j = 0; j < 8; j++) hv[j] = (half_t)Wt[kq + j][nt * 16 + l15];
    *(half8*)&out[((nt * nks + ks) * 64 + lane) * 8] = hv;
  }
}

// ---------------------------------------------------------------------------
// conv_l0: Z = conv3x3(feat, W0) + b0, position-major fp16 Z[pos][256].
// Wave-autonomous: each wave owns 16 positions, streams weight frags from L2,
// stages its own Xc chunk. ZERO barriers. k-order is (w9, c): chunk ks has
// fixed shift w9 = ks>>1 and 32 consecutive channels -> coalesced loads,
// shift math is shifts/masks only.
// ---------------------------------------------------------------------------
__global__ __launch_bounds__(256, 2) void conv_l0(
    const float* __restrict__ feat, const half_t* __restrict__ w0p,
    const float* __restrict__ b0, half_t* __restrict__ Z) {
  __shared__ alignas(16) half_t Xc[2][64][40];
  const int tid = threadIdx.x;
  const int lane = tid & 63, wave = tid >> 6, quad = lane >> 4, l15 = lane & 15;
  const int blk = blockIdx.x;
  const int b = blk >> 8;
  const int h = (blk >> 1) & 127;
  const int wbase = (blk & 1) << 6;
  const float* featB = feat + b * (64 * 128 * 128);

  const int xp = lane & 15;  // position within wave's 16-slice
  const int g = lane >> 4;   // k sub-group

  auto stage = [&](int ks, int buf) {
    const int w9 = ks >> 1;         // shift index 0..8
    const int di = w9 / 3;          // compiler magic-mul
    const int dj = w9 - 3 * di;
    const int y = h + di - 1;
    const int x = wbase + wave * 16 + xp + dj - 1;
    const bool ok = ((unsigned)y < 128u) && ((unsigned)x < 128u);
    const float* base = featB + (((ks & 1) << 5) << 14) + (y << 7) + x;
#pragma unroll
    for (int e = 0; e < 2; e++) {
      const int klocal = e * 16 + g * 4;
      half4 hv;
#pragma unroll
      for (int u = 0; u < 4; u++) {
        float v = 0.0f;
        if (ok) v = base[(klocal + u) << 14];
        hv[u] = (half_t)v;
      }
      *(half4*)&Xc[buf][wave * 16 + xp][klocal] = hv;
    }
  };

  const float4v zero4 = {0.0f, 0.0f, 0.0f, 0.0f};
  float4v acc[16];
#pragma unroll
  for (int nt = 0; nt < 16; nt++) acc[nt] = zero4;

  stage(0, 0);
#pragma unroll 1
  for (int ks = 0; ks < 18; ks++) {
    const int buf = ks & 1;
    if (ks + 1 < 18) stage(ks + 1, buf ^ 1);
    const half8 xf = *(const half8*)&Xc[buf][wave * 16 + l15][quad * 8];
#pragma unroll
    for (int grp = 0; grp < 2; grp++) {
      half8 wf[8];
#pragma unroll
      for (int i = 0; i < 8; i++)
        wf[i] = *(const half8*)(w0p + (((grp * 8 + i) * 18 + ks) * 64 + lane) * 8);
#pragma unroll
      for (int i = 0; i < 8; i++)
        acc[grp * 8 + i] = MFMA16(wf[i], xf, acc[grp * 8 + i]);  // D[n][pos]
    }
  }

  const int posbase = b * 16384 + h * 128 + wbase + wave * 16 + l15;
#pragma unroll
  for (int nt = 0; nt < 16; nt++) {
    const float4v bb4 = *(const float4v*)(b0 + nt * 16 + quad * 4);
    half4 hv;
#pragma unroll
    for (int rr = 0; rr < 4; rr++) hv[rr] = (half_t)(acc[nt][rr] + bb4[rr]);
    *(half4*)&Z[(size_t)posbase * 256 + nt * 16 + quad * 4] = hv;
  }
}

// ---------------------------------------------------------------------------
// liif_main: wave-autonomous. Each wave owns 32 rows (one corner-half) and all
// 256 N, streaming weight frags from L2/L1. L1..L3 barrier-free (wave-private
// Hs rows); one barrier per pass (Sp publish before ensemble).
// ---------------------------------------------------------------------------
__global__ __launch_bounds__(256, 2) void liif_main(
    const float* __restrict__ coord, const float* __restrict__ cell,
    const half_t* __restrict__ Zp, const half_t* __restrict__ wtp,
    const half_t* __restrict__ w1p, const half_t* __restrict__ w2p,
    const half_t* __restrict__ w3p, const half_t* __restrict__ w4p,
    const float* __restrict__ b1, const float* __restrict__ b2,
    const float* __restrict__ b3, const float* __restrict__ b4,
    float* __restrict__ outp) {
  __shared__ alignas(16) half_t Hs[128][264];  // 67584 B
  __shared__ float Sp[2][128][4];              // 4096 B (double-buffered preds)
  __shared__ int pos4[4][64];
  __shared__ half_t relxh[4][64], relyh[4][64];
  __shared__ half_t cellxh[64], cellyh[64];
  __shared__ float area4[4][64];
  __shared__ float oacc[64][4];

  const int tid = threadIdx.x;
  const int lane = tid & 63;
  const int wave = tid >> 6;
  const int quad = lane >> 4;
  const int l15 = lane & 15;
  const int blk = blockIdx.x;
  const int batch = blk >> 10;

  // ---- geometry ----
  {
    const int t = tid >> 6, row = tid & 63;
    const int gq = blk * 64 + row;
    const float cx0 = coord[gq * 2 + 0], cy0 = coord[gq * 2 + 1];
    const float vx = (t & 2) ? 1.0f : -1.0f;
    const float vy = (t & 1) ? 1.0f : -1.0f;
    const float r = 1.0f / 128.0f, lim = 1.0f - 1e-6f, eps = 1e-6f;
    float cx = fminf(fmaxf(cx0 + vx * r + eps, -lim), lim);
    float cy = fminf(fmaxf(cy0 + vy * r + eps, -lim), lim);
    int ix = (int)floorf((cx + 1.0f) * 64.0f);
    ix = min(max(ix, 0), 127);
    int iy = (int)floorf((cy + 1.0f) * 64.0f);
    iy = min(max(iy, 0), 127);
    float qx = -1.0f + (2.0f * ix + 1.0f) * (1.0f / 128.0f);
    float qy = -1.0f + (2.0f * iy + 1.0f) * (1.0f / 128.0f);
    float rxv = (cx0 - qx) * 128.0f;
    float ryv = (cy0 - qy) * 128.0f;
    pos4[t][row] = (batch << 14) + (ix << 7) + iy;
    relxh[t][row] = (half_t)rxv;
    relyh[t][row] = (half_t)ryv;
    area4[t][row] = fabsf(rxv * ryv) + 1e-9f;
    if (t == 0) {
      cellxh[row] = (half_t)(cell[gq * 2 + 0] * 128.0f);
      cellyh[row] = (half_t)(cell[gq * 2 + 1] * 128.0f);
      oacc[row][0] = 0.0f;
      oacc[row][1] = 0.0f;
      oacc[row][2] = 0.0f;
    }
  }
  __syncthreads();

  const float4v zero4 = {0.0f, 0.0f, 0.0f, 0.0f};
  const half8 zero8 = {0, 0, 0, 0, 0, 0, 0, 0};
  const int c8 = lane & 31;  // 8-channel block for gather
  const int rh = lane >> 5;  // row parity for gather

  const half8 wt0 = *(const half8*)(wtp + 0 * 256 + c8 * 8);
  const half8 wt1 = *(const half8*)(wtp + 1 * 256 + c8 * 8);
  const half8 wt2 = *(const half8*)(wtp + 2 * 256 + c8 * 8);
  const half8 wt3 = *(const half8*)(wtp + 3 * 256 + c8 * 8);

  const int corner0 = wave >> 1;       // 0/1 within pass
  const int qbase = (wave & 1) * 32;   // wave's query sub-range
  const int rwave = wave * 32;         // wave's private Hs rows

#pragma unroll 1
  for (int p = 0; p < 2; p++) {
    const int corner = 2 * p + corner0;
    // ---- gather Z + fp16 rank-4 + ReLU -> wave-private Hs rows ----
#pragma unroll
    for (int e = 0; e < 16; e++) {
      const int i = 2 * e + rh;
      const int qrow = qbase + i;
      const int pos = pos4[corner][qrow];
      const half8 z = *(const half8*)(Zp + ((size_t)pos << 8) + c8 * 8);
      const half_t rx = relxh[corner][qrow], ry = relyh[corner][qrow];
      const half_t cx = cellxh[qrow], cy = cellyh[qrow];
      const half8 rx8 = {rx, rx, rx, rx, rx, rx, rx, rx};
      const half8 ry8 = {ry, ry, ry, ry, ry, ry, ry, ry};
      const half8 cx8 = {cx, cx, cx, cx, cx, cx, cx, cx};
      const half8 cy8 = {cy, cy, cy, cy, cy, cy, cy, cy};
      half8 v = z + rx8 * wt0 + ry8 * wt1 + cx8 * wt2 + cy8 * wt3;
      v = __builtin_elementwise_max(v, zero8);
      *(half8*)&Hs[rwave + i][c8 * 8] = v;
    }
    // no barrier: rows are wave-private from here on

    // ---- layers 1..3: per-wave M=32, N=256, K=256; weights streamed ----
#pragma unroll 1
    for (int L = 0; L < 3; L++) {
      const half_t* wp = (L == 0) ? w1p : (L == 1) ? w2p : w3p;
      const float* bp = (L == 0) ? b1 : (L == 1) ? b2 : b3;
      float4v acc[2][16];
#pragma unroll
      for (int mt = 0; mt < 2; mt++)
#pragma unroll
        for (int nt = 0; nt < 16; nt++) acc[mt][nt] = zero4;
#pragma unroll 1
      for (int ks = 0; ks < 8; ks++) {
        const half8 xf0 = *(const half8*)&Hs[rwave + l15][ks * 32 + quad * 8];
        const half8 xf1 = *(const half8*)&Hs[rwave + 16 + l15][ks * 32 + quad * 8];
#pragma unroll
        for (int grp = 0; grp < 2; grp++) {
          half8 wf[8];
#pragma unroll
          for (int i = 0; i < 8; i++)
            wf[i] = *(const half8*)(wp + (((grp * 8 + i) * 8 + ks) * 64 + lane) * 8);
#pragma unroll
          for (int i = 0; i < 8; i++) {
            const int nt = grp * 8 + i;
            acc[0][nt] = MFMA16(wf[i], xf0, acc[0][nt]);  // D[n][q]
            acc[1][nt] = MFMA16(wf[i], xf1, acc[1][nt]);
          }
        }
      }
      // epilogue: bias + ReLU, b64 writes back to wave-private rows
#pragma unroll
      for (int nt = 0; nt < 16; nt++) {
        const float4v bb4 = *(const float4v*)(bp + nt * 16 + quad * 4);
        half4 h0, h1;
#pragma unroll
        for (int rr = 0; rr < 4; rr++) {
          h0[rr] = (half_t)fmaxf(acc[0][nt][rr] + bb4[rr], 0.0f);
          h1[rr] = (half_t)fmaxf(acc[1][nt][rr] + bb4[rr], 0.0f);
        }
        *(half4*)&Hs[rwave + l15][nt * 16 + quad * 4] = h0;
        *(half4*)&Hs[rwave + 16 + l15][nt * 16 + quad * 4] = h1;
      }
    }

    // ---- layer 4: 256 -> 3, full K per wave (standard orientation) ----
    float4v a4[2];
    a4[0] = zero4;
    a4[1] = zero4;
#pragma unroll
    for (int ks = 0; ks < 8; ks++) {
      const half8 bf = *(const half8*)(w4p + (ks * 64 + lane) * 8);
      const half8 a0 = *(const half8*)&Hs[rwave + l15][ks * 32 + quad * 8];
      const half8 a1 = *(const half8*)&Hs[rwave + 16 + l15][ks * 32 + quad * 8];
      a4[0] = MFMA16(a0, bf, a4[0]);
      a4[1] = MFMA16(a1, bf, a4[1]);
    }
    if (l15 < 4) {
#pragma unroll
      for (int mt = 0; mt < 2; mt++)
#pragma unroll
        for (int rr = 0; rr < 4; rr++)
          Sp[p][rwave + mt * 16 + quad * 4 + rr][l15] = a4[mt][rr];
    }
    __syncthreads();  // publish Sp (only barrier in the pass)

    // ---- ensemble (diagonal swap: opp = 3 - corner) ----
    if (tid < 192) {
      const int qrow = tid / 3;
      const int j = tid - qrow * 3;
      const float pa = b4[j] + Sp[p][qrow][j];         // corner 2p
      const float pb = b4[j] + Sp[p][64 + qrow][j];    // corner 2p+1
      oacc[qrow][j] += pa * area4[3 - 2 * p][qrow] + pb * area4[2 - 2 * p][qrow];
    }
  }

  if (tid < 192) {
    const int qrow = tid / 3;
    const int j = tid - qrow * 3;
    const float tot =
        area4[0][qrow] + area4[1][qrow] + area4[2][qrow] + area4[3][qrow];
    outp[(blk * 64 + qrow) * 3 + j] = oacc[qrow][j] / tot;
  }
}

// ---------------------------------------------------------------------------
extern "C" void kernel_launch(void* const* d_in, const int* in_sizes, int n_in,
                              void* d_out, int out_size, void* d_ws, size_t ws_size,
                              hipStream_t stream) {
  const float* feat = (const float*)d_in[0];
  const float* coord = (const float*)d_in[1];
  const float* cell = (const float*)d_in[2];
  const float* w0 = (const float*)d_in[3];
  const float* b0 = (const float*)d_in[4];
  const float* w1 = (const float*)d_in[5];
  const float* b1 = (const float*)d_in[6];
  const float* w2 = (const float*)d_in[7];
  const float* b2 = (const float*)d_in[8];
  const float* w3 = (const float*)d_in[9];
  const float* b3 = (const float*)d_in[10];
  const float* w4 = (const float*)d_in[11];
  const float* b4 = (const float*)d_in[12];

  half_t* w0p = (half_t*)d_ws;         // 16nt*18ks*512 = 147456 halves
  half_t* w1p = w0p + 147456;          // 65536
  half_t* w2p = w1p + 65536;
  half_t* w3p = w2p + 65536;
  half_t* w4p = w3p + 65536;           // 4096
  half_t* wtp = w4p + 4096;            // 1024
  half_t* Z = (half_t*)d_ws + 524288;  // [2*16384][256] fp16 (16.8 MB)

  pack_frags<<<43, 256, 0, stream>>>(w0, w1, w2, w3, w4, w0p, w1p, w2p, w3p, w4p, wtp);
  conv_l0<<<512, 256, 0, stream>>>(feat, w0p, b0, Z);
  liif_main<<<2048, 256, 0, stream>>>(coord, cell, Z, wtp, w1p, w2p, w3p, w4p, b1, b2,
                                      b3, b4, (float*)d_out);
}

// Round 7
// 326.423 us; speedup vs baseline: 1.5775x; 1.5775x over previous
//
#include <hip/hip_runtime.h>

typedef _Float16 half_t;
typedef _Float16 half4 __attribute__((ext_vector_type(4)));
typedef _Float16 half8 __attribute__((ext_vector_type(8)));
typedef float float4v __attribute__((ext_vector_type(4)));

#define MFMA16(a, b, c) __builtin_amdgcn_mfma_f32_16x16x32_f16(a, b, c, 0, 0, 0)

// Hidden-channel storage permutation: storage index s holds logical channel
// sigma(s). sigma swaps bits [5:4] <-> [3:2]. Chosen so a D-fragment lane's
// 16 values (jn x rr) are CONTIGUOUS in storage -> b128 epilogue writes.
__device__ __host__ __forceinline__ int sigma_p(int s) {
  return (s & 0xC3) | ((s & 0x0C) << 2) | ((s & 0x30) >> 2);
}

// ---------------------------------------------------------------------------
// pack_frags: weight packing into MFMA fragment order (fp16) via LDS transpose.
//   frag: out[((nt*nks+ks)*64+lane)*8+j] = W[krow][nt*16+(lane&15)]
// w0 (blocks 0..17): krow reordered (w9,c) for conv staging.
// w1..w3 (18..41): krow = sigma(k) (input side is in permuted storage order).
// block 42: w4 frags (krow=sigma) + w0 tail -> wtp[e][s] = tail[e][sigma(s)].
// ---------------------------------------------------------------------------
__global__ __launch_bounds__(256) void pack_frags(
    const float* __restrict__ w0, const float* __restrict__ w1,
    const float* __restrict__ w2, const float* __restrict__ w3,
    const float* __restrict__ w4, half_t* __restrict__ w0p,
    half_t* __restrict__ w1p, half_t* __restrict__ w2p,
    half_t* __restrict__ w3p, half_t* __restrict__ w4p,
    half_t* __restrict__ wtp) {
  const int bb = blockIdx.x;
  const int tid = threadIdx.x;
  if (bb == 42) {  // w4 frags (nt=0, nks=8) + w0 tail
#pragma unroll
    for (int e = 0; e < 16; e++) {
      const int id = e * 256 + tid;
      const int j = id & 7;
      const int lane = (id >> 3) & 63;
      const int ks = id >> 9;  // 0..7
      const int n = lane & 15;
      const int k = ks * 32 + ((lane >> 4) << 3) + j;
      w4p[id] = (half_t)((n < 3) ? w4[sigma_p(k) * 3 + n] : 0.0f);
    }
#pragma unroll
    for (int e = 0; e < 4; e++)
      wtp[e * 256 + tid] = (half_t)w0[576 * 256 + e * 256 + sigma_p(tid)];
    return;
  }
  __shared__ float Wt[32][260];
  const float* w;
  half_t* out;
  int nks, ks;
  int mode;  // 0 = w0 (w9,c) reorder, 1 = sigma rows
  if (bb < 18) { w = w0; out = w0p; nks = 18; ks = bb; mode = 0; }
  else if (bb < 26) { w = w1; out = w1p; nks = 8; ks = bb - 18; mode = 1; }
  else if (bb < 34) { w = w2; out = w2p; nks = 8; ks = bb - 26; mode = 1; }
  else { w = w3; out = w3p; nks = 8; ks = bb - 34; mode = 1; }
  {
    const int n4 = (tid & 63) * 4;
    const int kr = tid >> 6;
#pragma unroll
    for (int e = 0; e < 8; e++) {
      const int kp = e * 4 + kr;  // 0..31
      int kg = ks * 32 + kp;
      if (mode == 0) { const int w9 = kg >> 6, c = kg & 63; kg = c * 9 + w9; }
      else kg = sigma_p(kg);
      *(float4v*)&Wt[kp][n4] = *(const float4v*)(w + (size_t)kg * 256 + n4);
    }
  }
  __syncthreads();
  const int lane = tid & 63;
  const int l15 = lane & 15;
  const int kq = (lane >> 4) << 3;
#pragma unroll
  for (int e = 0; e < 4; e++) {
    const int nt = e * 4 + (tid >> 6);
    half8 hv;
#pragma unroll
    for (int j = 0; j < 8; j++) hv[j] = (half_t)Wt[kq + j][nt * 16 + l15];
    *(half8*)&out[((nt * nks + ks) * 64 + lane) * 8] = hv;
  }
}

// ---------------------------------------------------------------------------
// conv_l0: Z = conv3x3(feat, W0) + b0, position-major fp16 Z[pos][256],
// channels in S-storage order. Shared Xc staging (coalesced, via (w9,c)
// k-order), per-wave 64-col N-slices, swapped MFMA, dwordx4 Z stores.
// ---------------------------------------------------------------------------
__global__ __launch_bounds__(256, 2) void conv_l0(
    const float* __restrict__ feat, const half_t* __restrict__ w0p,
    const float* __restrict__ b0, half_t* __restrict__ Z) {
  __shared__ alignas(16) half_t Xc[2][64][40];
  const int tid = threadIdx.x;
  const int lane = tid & 63, wave = tid >> 6, quad = lane >> 4, l15 = lane & 15;
  const int blk = blockIdx.x;
  const int b = blk >> 8;
  const int h = (blk >> 1) & 127;
  const int wbase = (blk & 1) << 6;
  const float* featB = feat + b * (64 * 128 * 128);

  // coalesced staging: chunk ks = fixed shift w9=ks>>1, 32 consecutive chans
  auto stage = [&](int ks, int buf) {
    const int w9 = ks >> 1;
    const int di = w9 / 3;
    const int dj = w9 - 3 * di;
    const int pos = tid & 63;
    const int grp = tid >> 6;  // 8-channel sub-block
    const int y = h + di - 1;
    const int x = wbase + pos + dj - 1;
    const bool ok = ((unsigned)y < 128u) && ((unsigned)x < 128u);
    const float* base = featB + (((ks & 1) * 32 + grp * 8) << 14) + (y << 7) + x;
    half4 h0, h1;
#pragma unroll
    for (int u = 0; u < 4; u++) h0[u] = (half_t)(ok ? base[u << 14] : 0.0f);
#pragma unroll
    for (int u = 0; u < 4; u++) h1[u] = (half_t)(ok ? base[(u + 4) << 14] : 0.0f);
    *(half4*)&Xc[buf][pos][grp * 8] = h0;
    *(half4*)&Xc[buf][pos][grp * 8 + 4] = h1;
  };

  const float4v zero4 = {0.0f, 0.0f, 0.0f, 0.0f};
  float4v acc[4][4];
#pragma unroll
  for (int mt = 0; mt < 4; mt++)
#pragma unroll
    for (int jn = 0; jn < 4; jn++) acc[mt][jn] = zero4;

  half8 bcur[4], bnxt[4];
#pragma unroll
  for (int jn = 0; jn < 4; jn++)
    bcur[jn] = *(const half8*)(w0p + ((((wave * 4 + jn) * 18 + 0) * 64 + lane) << 3));
  stage(0, 0);
  __syncthreads();

#pragma unroll 1
  for (int ks = 0; ks < 18; ks++) {
    const int buf = ks & 1;
    if (ks + 1 < 18) {
      stage(ks + 1, buf ^ 1);
#pragma unroll
      for (int jn = 0; jn < 4; jn++)
        bnxt[jn] =
            *(const half8*)(w0p + ((((wave * 4 + jn) * 18 + ks + 1) * 64 + lane) << 3));
    }
    half8 a[4];
#pragma unroll
    for (int mt = 0; mt < 4; mt++)
      a[mt] = *(const half8*)(&Xc[buf][mt * 16 + l15][quad * 8]);
#pragma unroll
    for (int mt = 0; mt < 4; mt++)
#pragma unroll
      for (int jn = 0; jn < 4; jn++)
        acc[mt][jn] = MFMA16(bcur[jn], a[mt], acc[mt][jn]);  // D[n][pos]
#pragma unroll
    for (int jn = 0; jn < 4; jn++) bcur[jn] = bnxt[jn];
    __syncthreads();
  }

  // epilogue: S-order -> lane's 16 values contiguous -> 2x 16B stores per mt
  float4v bb[4];
#pragma unroll
  for (int jn = 0; jn < 4; jn++)
    bb[jn] = *(const float4v*)(b0 + (wave * 4 + jn) * 16 + quad * 4);
  const int posbase = b * 16384 + h * 128 + wbase;
#pragma unroll
  for (int mt = 0; mt < 4; mt++) {
    half8 o0, o1;
#pragma unroll
    for (int jn = 0; jn < 2; jn++)
#pragma unroll
      for (int rr = 0; rr < 4; rr++) {
        o0[jn * 4 + rr] = (half_t)(acc[mt][jn][rr] + bb[jn][rr]);
        o1[jn * 4 + rr] = (half_t)(acc[mt][jn + 2][rr] + bb[jn + 2][rr]);
      }
    half_t* zp = &Z[(size_t)(posbase + mt * 16 + l15) * 256 + wave * 64 + quad * 16];
    *(half8*)zp = o0;
    *(half8*)(zp + 8) = o1;
  }
}

// ---------------------------------------------------------------------------
// liif_main (R5 structure + S-order epilogue): M=128 tiles (64 q x 2 corners),
// 2 blocks/CU, shared Hs, per-wave 64-col weight slices streamed from L2.
// Epilogue: 2 conflict-free ds_write_b128 per mt.
// ---------------------------------------------------------------------------
__global__ __launch_bounds__(256, 2) void liif_main(
    const float* __restrict__ coord, const float* __restrict__ cell,
    const half_t* __restrict__ Zp, const half_t* __restrict__ wtp,
    const half_t* __restrict__ w1p, const half_t* __restrict__ w2p,
    const half_t* __restrict__ w3p, const half_t* __restrict__ w4p,
    const float* __restrict__ b1, const float* __restrict__ b2,
    const float* __restrict__ b3, const float* __restrict__ b4,
    float* __restrict__ outp) {
  __shared__ alignas(16) half_t Hs[128][264];  // 67584 B
  __shared__ float S4[4][128][4];              // 8192 B
  __shared__ int pos4[4][64];
  __shared__ half_t relxh[4][64], relyh[4][64];
  __shared__ half_t cellxh[64], cellyh[64];
  __shared__ float area4[4][64];
  __shared__ float oacc[64][4];

  const int tid = threadIdx.x;
  const int lane = tid & 63;
  const int wave = tid >> 6;
  const int quad = lane >> 4;
  const int l15 = lane & 15;
  const int blk = blockIdx.x;
  const int batch = blk >> 10;

  // ---- geometry ----
  {
    const int t = tid >> 6, row = tid & 63;
    const int gq = blk * 64 + row;
    const float cx0 = coord[gq * 2 + 0], cy0 = coord[gq * 2 + 1];
    const float vx = (t & 2) ? 1.0f : -1.0f;
    const float vy = (t & 1) ? 1.0f : -1.0f;
    const float r = 1.0f / 128.0f, lim = 1.0f - 1e-6f, eps = 1e-6f;
    float cx = fminf(fmaxf(cx0 + vx * r + eps, -lim), lim);
    float cy = fminf(fmaxf(cy0 + vy * r + eps, -lim), lim);
    int ix = (int)floorf((cx + 1.0f) * 64.0f);
    ix = min(max(ix, 0), 127);
    int iy = (int)floorf((cy + 1.0f) * 64.0f);
    iy = min(max(iy, 0), 127);
    float qx = -1.0f + (2.0f * ix + 1.0f) * (1.0f / 128.0f);
    float qy = -1.0f + (2.0f * iy + 1.0f) * (1.0f / 128.0f);
    float rxv = (cx0 - qx) * 128.0f;
    float ryv = (cy0 - qy) * 128.0f;
    pos4[t][row] = (batch << 14) + (ix << 7) + iy;
    relxh[t][row] = (half_t)rxv;
    relyh[t][row] = (half_t)ryv;
    area4[t][row] = fabsf(rxv * ryv) + 1e-9f;
    if (t == 0) {
      cellxh[row] = (half_t)(cell[gq * 2 + 0] * 128.0f);
      cellyh[row] = (half_t)(cell[gq * 2 + 1] * 128.0f);
      oacc[row][0] = 0.0f;
      oacc[row][1] = 0.0f;
      oacc[row][2] = 0.0f;
    }
  }
  __syncthreads();

  const float4v zero4 = {0.0f, 0.0f, 0.0f, 0.0f};
  const half8 zero8 = {0, 0, 0, 0, 0, 0, 0, 0};
  const int c8 = tid & 31;            // fixed 8-channel (storage) block
  const int rbase = (tid >> 5) * 16;  // rows rbase..rbase+15

  const half8 wt0 = *(const half8*)(wtp + 0 * 256 + c8 * 8);
  const half8 wt1 = *(const half8*)(wtp + 1 * 256 + c8 * 8);
  const half8 wt2 = *(const half8*)(wtp + 2 * 256 + c8 * 8);
  const half8 wt3 = *(const half8*)(wtp + 3 * 256 + c8 * 8);

  half8 bcur[4], bnxt[4], bf4[2];
#pragma unroll
  for (int jn = 0; jn < 4; jn++)
    bcur[jn] = *(const half8*)(w1p + ((((wave * 4 + jn) * 8 + 0) * 64 + lane) << 3));

#pragma unroll 1
  for (int p = 0; p < 2; p++) {
    // ---- gather Z + fp16 rank-4 + ReLU -> Hs ----
#pragma unroll
    for (int e = 0; e < 16; e++) {
      const int r = rbase + e;
      const int corner = 2 * p + (r >> 6);
      const int qrow = r & 63;
      const half8 z = *(const half8*)(Zp + ((size_t)pos4[corner][qrow] << 8) + c8 * 8);
      const half_t rx = relxh[corner][qrow], ry = relyh[corner][qrow];
      const half_t cx = cellxh[qrow], cy = cellyh[qrow];
      const half8 rx8 = {rx, rx, rx, rx, rx, rx, rx, rx};
      const half8 ry8 = {ry, ry, ry, ry, ry, ry, ry, ry};
      const half8 cx8 = {cx, cx, cx, cx, cx, cx, cx, cx};
      const half8 cy8 = {cy, cy, cy, cy, cy, cy, cy, cy};
      half8 v = z + rx8 * wt0 + ry8 * wt1 + cx8 * wt2 + cy8 * wt3;
      v = __builtin_elementwise_max(v, zero8);
      *(half8*)(&Hs[r][c8 * 8]) = v;
    }
    __syncthreads();

    // ---- layers 1..3: M=128, N=256 (4x64 over waves), K=256 (swapped) ----
    float4v acc[8][4];
#pragma unroll 1
    for (int L = 0; L < 3; L++) {
      const half_t* wp = (L == 0) ? w1p : (L == 1) ? w2p : w3p;
      const float* bp = (L == 0) ? b1 : (L == 1) ? b2 : b3;
#pragma unroll
      for (int mt = 0; mt < 8; mt++)
#pragma unroll
        for (int jn = 0; jn < 4; jn++) acc[mt][jn] = zero4;
#pragma unroll 1
      for (int ks = 0; ks < 8; ks++) {
        if (ks + 1 < 8) {
#pragma unroll
          for (int jn = 0; jn < 4; jn++)
            bnxt[jn] =
                *(const half8*)(wp + ((((wave * 4 + jn) * 8 + ks + 1) * 64 + lane) << 3));
        }
        half8 a[8];
#pragma unroll
        for (int mt = 0; mt < 8; mt++)
          a[mt] = *(const half8*)(&Hs[mt * 16 + l15][ks * 32 + quad * 8]);
#pragma unroll
        for (int mt = 0; mt < 8; mt++)
#pragma unroll
          for (int jn = 0; jn < 4; jn++)
            acc[mt][jn] = MFMA16(bcur[jn], a[mt], acc[mt][jn]);  // D[n][q]
#pragma unroll
        for (int jn = 0; jn < 4; jn++) bcur[jn] = bnxt[jn];
      }
      __syncthreads();  // all waves done READING Hs
      // preload next GEMM's first fragments (overlaps epilogue)
      if (L < 2) {
        const half_t* wpn = (L == 0) ? w2p : w3p;
#pragma unroll
        for (int jn = 0; jn < 4; jn++)
          bcur[jn] = *(const half8*)(wpn + ((((wave * 4 + jn) * 8 + 0) * 64 + lane) << 3));
      } else {
#pragma unroll
        for (int kx = 0; kx < 2; kx++)
          bf4[kx] = *(const half8*)(w4p + (((wave * 2 + kx) * 64 + lane) << 3));
      }
      // S-order epilogue: lane's 16 outputs contiguous -> 2x ds_write_b128
      float4v bb[4];
#pragma unroll
      for (int jn = 0; jn < 4; jn++)
        bb[jn] = *(const float4v*)(bp + (wave * 4 + jn) * 16 + quad * 4);
#pragma unroll
      for (int mt = 0; mt < 8; mt++) {
        half8 o0, o1;
#pragma unroll
        for (int jn = 0; jn < 2; jn++)
#pragma unroll
          for (int rr = 0; rr < 4; rr++) {
            o0[jn * 4 + rr] = (half_t)fmaxf(acc[mt][jn][rr] + bb[jn][rr], 0.0f);
            o1[jn * 4 + rr] = (half_t)fmaxf(acc[mt][jn + 2][rr] + bb[jn + 2][rr], 0.0f);
          }
        half_t* hp = &Hs[mt * 16 + l15][wave * 64 + quad * 16];
        *(half8*)hp = o0;
        *(half8*)(hp + 8) = o1;
      }
      __syncthreads();
    }

    // ---- layer 4: 256 -> 3, K split across waves (standard orientation) ----
    float4v acc4[8];
#pragma unroll
    for (int mt = 0; mt < 8; mt++) acc4[mt] = zero4;
#pragma unroll
    for (int kx = 0; kx < 2; kx++) {
      const int ks = wave * 2 + kx;
#pragma unroll
      for (int mt = 0; mt < 8; mt++) {
        half8 a = *(const half8*)(&Hs[mt * 16 + l15][ks * 32 + quad * 8]);
        acc4[mt] = MFMA16(a, bf4[kx], acc4[mt]);
      }
    }
    if (l15 < 4) {
#pragma unroll
      for (int mt = 0; mt < 8; mt++)
#pragma unroll
        for (int rr = 0; rr < 4; rr++)
          S4[wave][mt * 16 + quad * 4 + rr][l15] = acc4[mt][rr];
    }
    __syncthreads();

    // preload next pass's L1 first fragments (overlaps ensemble)
    if (p == 0) {
#pragma unroll
      for (int jn = 0; jn < 4; jn++)
        bcur[jn] = *(const half8*)(w1p + ((((wave * 4 + jn) * 8 + 0) * 64 + lane) << 3));
    }

    // ---- 2-corner ensemble (diagonal swap: opp = 3 - corner) ----
    if (tid < 192) {
      const int qrow = tid / 3;
      const int j = tid - qrow * 3;
      const int ca = 2 * p, cb = 2 * p + 1;
      float pa = b4[j] + S4[0][qrow][j] + S4[1][qrow][j] + S4[2][qrow][j] + S4[3][qrow][j];
      float pb = b4[j] + S4[0][qrow + 64][j] + S4[1][qrow + 64][j] +
                 S4[2][qrow + 64][j] + S4[3][qrow + 64][j];
      oacc[qrow][j] += pa * area4[3 - ca][qrow] + pb * area4[3 - cb][qrow];
    }
    __syncthreads();
  }

  if (tid < 192) {
    const int qrow = tid / 3;
    const int j = tid - qrow * 3;
    const float tot =
        area4[0][qrow] + area4[1][qrow] + area4[2][qrow] + area4[3][qrow];
    outp[(blk * 64 + qrow) * 3 + j] = oacc[qrow][j] / tot;
  }
}

// ---------------------------------------------------------------------------
extern "C" void kernel_launch(void* const* d_in, const int* in_sizes, int n_in,
                              void* d_out, int out_size, void* d_ws, size_t ws_size,
                              hipStream_t stream) {
  const float* feat = (const float*)d_in[0];
  const float* coord = (const float*)d_in[1];
  const float* cell = (const float*)d_in[2];
  const float* w0 = (const float*)d_in[3];
  const float* b0 = (const float*)d_in[4];
  const float* w1 = (const float*)d_in[5];
  const float* b1 = (const float*)d_in[6];
  const float* w2 = (const float*)d_in[7];
  const float* b2 = (const float*)d_in[8];
  const float* w3 = (const float*)d_in[9];
  const float* b3 = (const float*)d_in[10];
  const float* w4 = (const float*)d_in[11];
  const float* b4 = (const float*)d_in[12];

  half_t* w0p = (half_t*)d_ws;         // 16nt*18ks*512 = 147456 halves
  half_t* w1p = w0p + 147456;          // 65536
  half_t* w2p = w1p + 65536;
  half_t* w3p = w2p + 65536;
  half_t* w4p = w3p + 65536;           // 4096
  half_t* wtp = w4p + 4096;            // 1024
  half_t* Z = (half_t*)d_ws + 524288;  // [2*16384][256] fp16 (16.8 MB)

  pack_frags<<<43, 256, 0, stream>>>(w0, w1, w2, w3, w4, w0p, w1p, w2p, w3p, w4p, wtp);
  conv_l0<<<512, 256, 0, stream>>>(feat, w0p, b0, Z);
  liif_main<<<2048, 256, 0, stream>>>(coord, cell, Z, wtp, w1p, w2p, w3p, w4p, b1, b2,
                                      b3, b4, (float*)d_out);
}

// Round 8
// 318.531 us; speedup vs baseline: 1.6166x; 1.0248x over previous
//
#include <hip/hip_runtime.h>

typedef _Float16 half_t;
typedef _Float16 half4 __attribute__((ext_vector_type(4)));
typedef _Float16 half8 __attribute__((ext_vector_type(8)));
typedef float float4v __attribute__((ext_vector_type(4)));

#define MFMA16(a, b, c) __builtin_amdgcn_mfma_f32_16x16x32_f16(a, b, c, 0, 0, 0)

// Hidden-channel storage permutation (swap bits [5:4] <-> [3:2]) so a D-frag
// lane's 16 outputs are contiguous in storage -> b128 epilogue writes.
__device__ __host__ __forceinline__ int sigma_p(int s) {
  return (s & 0xC3) | ((s & 0x0C) << 2) | ((s & 0x30) >> 2);
}

// ---------------------------------------------------------------------------
// pack_frags: weight packing into MFMA fragment order (fp16) via LDS transpose.
// w0 (blocks 0..17): krow reordered (w9,c). w1..w3: krow = sigma(k).
// block 42: w4 frags (krow=sigma) + w0 tail (cols sigma-permuted).
// ---------------------------------------------------------------------------
__global__ __launch_bounds__(256) void pack_frags(
    const float* __restrict__ w0, const float* __restrict__ w1,
    const float* __restrict__ w2, const float* __restrict__ w3,
    const float* __restrict__ w4, half_t* __restrict__ w0p,
    half_t* __restrict__ w1p, half_t* __restrict__ w2p,
    half_t* __restrict__ w3p, half_t* __restrict__ w4p,
    half_t* __restrict__ wtp) {
  const int bb = blockIdx.x;
  const int tid = threadIdx.x;
  if (bb == 42) {
#pragma unroll
    for (int e = 0; e < 16; e++) {
      const int id = e * 256 + tid;
      const int j = id & 7;
      const int lane = (id >> 3) & 63;
      const int ks = id >> 9;
      const int n = lane & 15;
      const int k = ks * 32 + ((lane >> 4) << 3) + j;
      w4p[id] = (half_t)((n < 3) ? w4[sigma_p(k) * 3 + n] : 0.0f);
    }
#pragma unroll
    for (int e = 0; e < 4; e++)
      wtp[e * 256 + tid] = (half_t)w0[576 * 256 + e * 256 + sigma_p(tid)];
    return;
  }
  __shared__ float Wt[32][260];
  const float* w;
  half_t* out;
  int nks, ks;
  int mode;
  if (bb < 18) { w = w0; out = w0p; nks = 18; ks = bb; mode = 0; }
  else if (bb < 26) { w = w1; out = w1p; nks = 8; ks = bb - 18; mode = 1; }
  else if (bb < 34) { w = w2; out = w2p; nks = 8; ks = bb - 26; mode = 1; }
  else { w = w3; out = w3p; nks = 8; ks = bb - 34; mode = 1; }
  {
    const int n4 = (tid & 63) * 4;
    const int kr = tid >> 6;
#pragma unroll
    for (int e = 0; e < 8; e++) {
      const int kp = e * 4 + kr;
      int kg = ks * 32 + kp;
      if (mode == 0) { const int w9 = kg >> 6, c = kg & 63; kg = c * 9 + w9; }
      else kg = sigma_p(kg);
      *(float4v*)&Wt[kp][n4] = *(const float4v*)(w + (size_t)kg * 256 + n4);
    }
  }
  __syncthreads();
  const int lane = tid & 63;
  const int l15 = lane & 15;
  const int kq = (lane >> 4) << 3;
#pragma unroll
  for (int e = 0; e < 4; e++) {
    const int nt = e * 4 + (tid >> 6);
    half8 hv;
#pragma unroll
    for (int j = 0; j < 8; j++) hv[j] = (half_t)Wt[kq + j][nt * 16 + l15];
    *(half8*)&out[((nt * nks + ks) * 64 + lane) * 8] = hv;
  }
}

// ---------------------------------------------------------------------------
// conv_l0: Z = conv3x3(feat, W0) + b0, position-major fp16 Z[pos][256]
// (channels in S-storage order). M=32 positions/block, 1024 blocks,
// 4 blocks/CU for TLP. Coalesced staging via (w9,c) k-order.
// ---------------------------------------------------------------------------
__global__ __launch_bounds__(256, 4) void conv_l0(
    const float* __restrict__ feat, const half_t* __restrict__ w0p,
    const float* __restrict__ b0, half_t* __restrict__ Z) {
  __shared__ alignas(16) half_t Xc[2][32][40];
  const int tid = threadIdx.x;
  const int lane = tid & 63, wave = tid >> 6, quad = lane >> 4, l15 = lane & 15;
  const int blk = blockIdx.x;
  const int b = blk >> 9;
  const int h = (blk >> 2) & 127;
  const int wbase = (blk & 3) << 5;
  const float* featB = feat + b * (64 * 128 * 128);

  // stage chunk ks: fixed shift w9=ks>>1, 32 consecutive channels.
  auto stage = [&](int ks, int buf) {
    const int w9 = ks >> 1;
    const int di = w9 / 3;
    const int dj = w9 - 3 * di;
    const int pos = tid & 31;
    const int grp = tid >> 5;  // 0..7: 4-channel sub-block
    const int y = h + di - 1;
    const int x = wbase + pos + dj - 1;
    const bool ok = ((unsigned)y < 128u) && ((unsigned)x < 128u);
    const float* base = featB + (((ks & 1) * 32 + grp * 4) << 14) + (y << 7) + x;
    half4 hv;
#pragma unroll
    for (int u = 0; u < 4; u++) hv[u] = (half_t)(ok ? base[u << 14] : 0.0f);
    *(half4*)&Xc[buf][pos][grp * 4] = hv;
  };

  const float4v zero4 = {0.0f, 0.0f, 0.0f, 0.0f};
  float4v acc[2][4];
#pragma unroll
  for (int mt = 0; mt < 2; mt++)
#pragma unroll
    for (int jn = 0; jn < 4; jn++) acc[mt][jn] = zero4;

  stage(0, 0);
  __syncthreads();

#pragma unroll 1
  for (int ks = 0; ks < 18; ks++) {
    const int buf = ks & 1;
    half8 bw[4];
#pragma unroll
    for (int jn = 0; jn < 4; jn++)
      bw[jn] = *(const half8*)(w0p + ((((wave * 4 + jn) * 18 + ks) * 64 + lane) << 3));
    half8 a[2];
#pragma unroll
    for (int mt = 0; mt < 2; mt++)
      a[mt] = *(const half8*)(&Xc[buf][mt * 16 + l15][quad * 8]);
    if (ks + 1 < 18) {
      __syncthreads();  // a[] loaded by all waves; safe to restage buf^1? no:
      // buf^1 is the OTHER buffer; only need sync before overwriting buf on
      // ks+2. Double buffer => stage into buf^1 now, sync at loop bottom.
      stage(ks + 1, buf ^ 1);
    }
#pragma unroll
    for (int mt = 0; mt < 2; mt++)
#pragma unroll
      for (int jn = 0; jn < 4; jn++)
        acc[mt][jn] = MFMA16(bw[jn], a[mt], acc[mt][jn]);  // D[n][pos]
    __syncthreads();
  }

  // epilogue: S-order -> lane's 16 values contiguous -> 2x 16B global stores
  float4v bb[4];
#pragma unroll
  for (int jn = 0; jn < 4; jn++)
    bb[jn] = *(const float4v*)(b0 + (wave * 4 + jn) * 16 + quad * 4);
  const int posbase = b * 16384 + h * 128 + wbase;
#pragma unroll
  for (int mt = 0; mt < 2; mt++) {
    half8 o0, o1;
#pragma unroll
    for (int jn = 0; jn < 2; jn++)
#pragma unroll
      for (int rr = 0; rr < 4; rr++) {
        o0[jn * 4 + rr] = (half_t)(acc[mt][jn][rr] + bb[jn][rr]);
        o1[jn * 4 + rr] = (half_t)(acc[mt][jn + 2][rr] + bb[jn + 2][rr]);
      }
    half_t* zp = &Z[(size_t)(posbase + mt * 16 + l15) * 256 + wave * 64 + quad * 16];
    *(half8*)zp = o0;
    *(half8*)(zp + 8) = o1;
  }
}

// ---------------------------------------------------------------------------
// liif_main: M=128 tiles (64 q x 2 corners), 2 blocks/CU. Hs stride 280
// halves (140 dw = 12 mod 32): A-frag b128 reads + S-order b128 writes hit
// the 4-clk LDS structural minimum (zero conflicts). S4 overlaid into Hs.
// ---------------------------------------------------------------------------
__global__ __launch_bounds__(256, 2) void liif_main(
    const float* __restrict__ coord, const float* __restrict__ cell,
    const half_t* __restrict__ Zp, const half_t* __restrict__ wtp,
    const half_t* __restrict__ w1p, const half_t* __restrict__ w2p,
    const half_t* __restrict__ w3p, const half_t* __restrict__ w4p,
    const float* __restrict__ b1, const float* __restrict__ b2,
    const float* __restrict__ b3, const float* __restrict__ b4,
    float* __restrict__ outp) {
  __shared__ alignas(16) half_t Hs[128][280];  // 71680 B
  __shared__ int pos4[4][64];
  __shared__ half_t relxh[4][64], relyh[4][64];
  __shared__ half_t cellxh[64], cellyh[64];
  __shared__ float area4[4][64];
  __shared__ float oacc[64][4];

  const int tid = threadIdx.x;
  const int lane = tid & 63;
  const int wave = tid >> 6;
  const int quad = lane >> 4;
  const int l15 = lane & 15;
  const int blk = blockIdx.x;
  const int batch = blk >> 10;

  // ---- geometry ----
  {
    const int t = tid >> 6, row = tid & 63;
    const int gq = blk * 64 + row;
    const float cx0 = coord[gq * 2 + 0], cy0 = coord[gq * 2 + 1];
    const float vx = (t & 2) ? 1.0f : -1.0f;
    const float vy = (t & 1) ? 1.0f : -1.0f;
    const float r = 1.0f / 128.0f, lim = 1.0f - 1e-6f, eps = 1e-6f;
    float cx = fminf(fmaxf(cx0 + vx * r + eps, -lim), lim);
    float cy = fminf(fmaxf(cy0 + vy * r + eps, -lim), lim);
    int ix = (int)floorf((cx + 1.0f) * 64.0f);
    ix = min(max(ix, 0), 127);
    int iy = (int)floorf((cy + 1.0f) * 64.0f);
    iy = min(max(iy, 0), 127);
    float qx = -1.0f + (2.0f * ix + 1.0f) * (1.0f / 128.0f);
    float qy = -1.0f + (2.0f * iy + 1.0f) * (1.0f / 128.0f);
    float rxv = (cx0 - qx) * 128.0f;
    float ryv = (cy0 - qy) * 128.0f;
    pos4[t][row] = (batch << 14) + (ix << 7) + iy;
    relxh[t][row] = (half_t)rxv;
    relyh[t][row] = (half_t)ryv;
    area4[t][row] = fabsf(rxv * ryv) + 1e-9f;
    if (t == 0) {
      cellxh[row] = (half_t)(cell[gq * 2 + 0] * 128.0f);
      cellyh[row] = (half_t)(cell[gq * 2 + 1] * 128.0f);
      oacc[row][0] = 0.0f;
      oacc[row][1] = 0.0f;
      oacc[row][2] = 0.0f;
    }
  }
  __syncthreads();

  const float4v zero4 = {0.0f, 0.0f, 0.0f, 0.0f};
  const half8 zero8 = {0, 0, 0, 0, 0, 0, 0, 0};
  const int c8 = tid & 31;
  const int rbase = (tid >> 5) * 16;

  const half8 wt0 = *(const half8*)(wtp + 0 * 256 + c8 * 8);
  const half8 wt1 = *(const half8*)(wtp + 1 * 256 + c8 * 8);
  const half8 wt2 = *(const half8*)(wtp + 2 * 256 + c8 * 8);
  const half8 wt3 = *(const half8*)(wtp + 3 * 256 + c8 * 8);

  half8 bcur[4], bnxt[4], bf4[2];
#pragma unroll
  for (int jn = 0; jn < 4; jn++)
    bcur[jn] = *(const half8*)(w1p + ((((wave * 4 + jn) * 8 + 0) * 64 + lane) << 3));

#pragma unroll 1
  for (int p = 0; p < 2; p++) {
    // ---- gather Z + fp16 rank-4 + ReLU -> Hs ----
#pragma unroll
    for (int e = 0; e < 16; e++) {
      const int r = rbase + e;
      const int corner = 2 * p + (r >> 6);
      const int qrow = r & 63;
      const half8 z = *(const half8*)(Zp + ((size_t)pos4[corner][qrow] << 8) + c8 * 8);
      const half_t rx = relxh[corner][qrow], ry = relyh[corner][qrow];
      const half_t cx = cellxh[qrow], cy = cellyh[qrow];
      const half8 rx8 = {rx, rx, rx, rx, rx, rx, rx, rx};
      const half8 ry8 = {ry, ry, ry, ry, ry, ry, ry, ry};
      const half8 cx8 = {cx, cx, cx, cx, cx, cx, cx, cx};
      const half8 cy8 = {cy, cy, cy, cy, cy, cy, cy, cy};
      half8 v = z + rx8 * wt0 + ry8 * wt1 + cx8 * wt2 + cy8 * wt3;
      v = __builtin_elementwise_max(v, zero8);
      *(half8*)(&Hs[r][c8 * 8]) = v;
    }
    __syncthreads();

    // ---- layers 1..3: M=128, N=256 (4x64 over waves), K=256 (swapped) ----
    float4v acc[8][4];
#pragma unroll 1
    for (int L = 0; L < 3; L++) {
      const half_t* wp = (L == 0) ? w1p : (L == 1) ? w2p : w3p;
      const float* bp = (L == 0) ? b1 : (L == 1) ? b2 : b3;
#pragma unroll
      for (int mt = 0; mt < 8; mt++)
#pragma unroll
        for (int jn = 0; jn < 4; jn++) acc[mt][jn] = zero4;
#pragma unroll 1
      for (int ks = 0; ks < 8; ks++) {
        if (ks + 1 < 8) {
#pragma unroll
          for (int jn = 0; jn < 4; jn++)
            bnxt[jn] =
                *(const half8*)(wp + ((((wave * 4 + jn) * 8 + ks + 1) * 64 + lane) << 3));
        }
        half8 a[8];
#pragma unroll
        for (int mt = 0; mt < 8; mt++)
          a[mt] = *(const half8*)(&Hs[mt * 16 + l15][ks * 32 + quad * 8]);
#pragma unroll
        for (int mt = 0; mt < 8; mt++)
#pragma unroll
          for (int jn = 0; jn < 4; jn++)
            acc[mt][jn] = MFMA16(bcur[jn], a[mt], acc[mt][jn]);  // D[n][q]
#pragma unroll
        for (int jn = 0; jn < 4; jn++) bcur[jn] = bnxt[jn];
      }
      __syncthreads();  // all waves done READING Hs
      if (L < 2) {
        const half_t* wpn = (L == 0) ? w2p : w3p;
#pragma unroll
        for (int jn = 0; jn < 4; jn++)
          bcur[jn] = *(const half8*)(wpn + ((((wave * 4 + jn) * 8 + 0) * 64 + lane) << 3));
      } else {
#pragma unroll
        for (int kx = 0; kx < 2; kx++)
          bf4[kx] = *(const half8*)(w4p + (((wave * 2 + kx) * 64 + lane) << 3));
      }
      // S-order epilogue: 2x ds_write_b128 per mt, conflict-free at stride 280
      float4v bb[4];
#pragma unroll
      for (int jn = 0; jn < 4; jn++)
        bb[jn] = *(const float4v*)(bp + (wave * 4 + jn) * 16 + quad * 4);
#pragma unroll
      for (int mt = 0; mt < 8; mt++) {
        half8 o0, o1;
#pragma unroll
        for (int jn = 0; jn < 2; jn++)
#pragma unroll
          for (int rr = 0; rr < 4; rr++) {
            o0[jn * 4 + rr] = (half_t)fmaxf(acc[mt][jn][rr] + bb[jn][rr], 0.0f);
            o1[jn * 4 + rr] = (half_t)fmaxf(acc[mt][jn + 2][rr] + bb[jn + 2][rr], 0.0f);
          }
        half_t* hp = &Hs[mt * 16 + l15][wave * 64 + quad * 16];
        *(half8*)hp = o0;
        *(half8*)(hp + 8) = o1;
      }
      __syncthreads();
    }

    // ---- layer 4: 256 -> 3, K split across waves ----
    float4v acc4[8];
#pragma unroll
    for (int mt = 0; mt < 8; mt++) acc4[mt] = zero4;
#pragma unroll
    for (int kx = 0; kx < 2; kx++) {
      const int ks = wave * 2 + kx;
#pragma unroll
      for (int mt = 0; mt < 8; mt++) {
        half8 a = *(const half8*)(&Hs[mt * 16 + l15][ks * 32 + quad * 8]);
        acc4[mt] = MFMA16(a, bf4[kx], acc4[mt]);
      }
    }
    __syncthreads();  // all Hs reads done -> overlay S4 into Hs
    float* S4f = (float*)&Hs[0][0];  // [wave][128][4] floats = 8 KB
    if (l15 < 4) {
#pragma unroll
      for (int mt = 0; mt < 8; mt++)
#pragma unroll
        for (int rr = 0; rr < 4; rr++)
          S4f[((wave * 128 + mt * 16 + quad * 4 + rr) << 2) + l15] = acc4[mt][rr];
    }
    __syncthreads();

    if (p == 0) {
#pragma unroll
      for (int jn = 0; jn < 4; jn++)
        bcur[jn] = *(const half8*)(w1p + ((((wave * 4 + jn) * 8 + 0) * 64 + lane) << 3));
    }

    // ---- 2-corner ensemble (diagonal swap: opp = 3 - corner) ----
    if (tid < 192) {
      const int qrow = tid / 3;
      const int j = tid - qrow * 3;
      const int ca = 2 * p, cb = 2 * p + 1;
      float pa = b4[j] + S4f[((0 * 128 + qrow) << 2) + j] +
                 S4f[((1 * 128 + qrow) << 2) + j] + S4f[((2 * 128 + qrow) << 2) + j] +
                 S4f[((3 * 128 + qrow) << 2) + j];
      float pb = b4[j] + S4f[((0 * 128 + 64 + qrow) << 2) + j] +
                 S4f[((1 * 128 + 64 + qrow) << 2) + j] +
                 S4f[((2 * 128 + 64 + qrow) << 2) + j] +
                 S4f[((3 * 128 + 64 + qrow) << 2) + j];
      oacc[qrow][j] += pa * area4[3 - ca][qrow] + pb * area4[3 - cb][qrow];
    }
    __syncthreads();  // S4f region reused as Hs next pass
  }

  if (tid < 192) {
    const int qrow = tid / 3;
    const int j = tid - qrow * 3;
    const float tot =
        area4[0][qrow] + area4[1][qrow] + area4[2][qrow] + area4[3][qrow];
    outp[(blk * 64 + qrow) * 3 + j] = oacc[qrow][j] / tot;
  }
}

// ---------------------------------------------------------------------------
extern "C" void kernel_launch(void* const* d_in, const int* in_sizes, int n_in,
                              void* d_out, int out_size, void* d_ws, size_t ws_size,
                              hipStream_t stream) {
  const float* feat = (const float*)d_in[0];
  const float* coord = (const float*)d_in[1];
  const float* cell = (const float*)d_in[2];
  const float* w0 = (const float*)d_in[3];
  const float* b0 = (const float*)d_in[4];
  const float* w1 = (const float*)d_in[5];
  const float* b1 = (const float*)d_in[6];
  const float* w2 = (const float*)d_in[7];
  const float* b2 = (const float*)d_in[8];
  const float* w3 = (const float*)d_in[9];
  const float* b3 = (const float*)d_in[10];
  const float* w4 = (const float*)d_in[11];
  const float* b4 = (const float*)d_in[12];

  half_t* w0p = (half_t*)d_ws;         // 147456 halves
  half_t* w1p = w0p + 147456;          // 65536
  half_t* w2p = w1p + 65536;
  half_t* w3p = w2p + 65536;
  half_t* w4p = w3p + 65536;           // 4096
  half_t* wtp = w4p + 4096;            // 1024
  half_t* Z = (half_t*)d_ws + 524288;  // [2*16384][256] fp16 (16.8 MB)

  pack_frags<<<43, 256, 0, stream>>>(w0, w1, w2, w3, w4, w0p, w1p, w2p, w3p, w4p, wtp);
  conv_l0<<<1024, 256, 0, stream>>>(feat, w0p, b0, Z);
  liif_main<<<2048, 256, 0, stream>>>(coord, cell, Z, wtp, w1p, w2p, w3p, w4p, b1, b2,
                                      b3, b4, (float*)d_out);
}